// Round 15
// baseline (283.415 us; speedup 1.0000x reference)
//
#include <hip/hip_runtime.h>

#define D 256
#define KDIM 512
#define BCAP 16384  // per-bucket staging capacity (avg fill 8192 for E=3.2M, B1=391)
#define EPB 8192    // edges per scatter block
#define BM 64       // rows per GEMM block

typedef __bf16 bf16_t;
typedef bf16_t bf16x8 __attribute__((ext_vector_type(8)));
typedef bf16_t bf16x4 __attribute__((ext_vector_type(4)));
typedef float f32x4_t __attribute__((ext_vector_type(4)));
typedef float f32x2_t __attribute__((ext_vector_type(2)));

// ---------------- device bodies (512-thread grid-partitioned super-kernels)

// coarse scatter into 256-node buckets (block-aggregated; write-amp ~1x)
__device__ __forceinline__ void scatter_body(int bid, const int* __restrict__ eidx,
                                             int* __restrict__ bcur,
                                             int* __restrict__ staging, int E,
                                             char* smem) {
    int* lhist = (int*)smem;        // [512]
    int* lcur = lhist + 512;        // [512]
    int* gbase = lcur + 512;        // [512]
    const int t = threadIdx.x;      // 0..511
    const int e0 = bid * EPB;
    int e1 = e0 + EPB;
    if (e1 > E) e1 = E;

    lhist[t] = 0;
    lcur[t] = 0;
    __syncthreads();

    for (int e = e0 + t; e < e1; e += 512) {
        int d = eidx[E + e];
        atomicAdd(&lhist[d >> 8], 1);
    }
    __syncthreads();

    {
        int c = lhist[t];
        gbase[t] = (c > 0) ? atomicAdd(&bcur[t * 16], c) : 0;
    }
    __syncthreads();

    for (int e = e0 + t; e < e1; e += 512) {
        int s = eidx[e];
        int d = eidx[E + e];
        int b = d >> 8;
        int pos = gbase[b] + atomicAdd(&lcur[b], 1);
        staging[(size_t)b * BCAP + pos] = ((d & 255) << 24) | s;  // s < 2^24
    }
}

// per-bucket hist + scan + counting-sort; emits row_ptr AND edge_src
__device__ __forceinline__ void bucket_body(int b, const int* __restrict__ bcur,
                                            const int* __restrict__ bbase,
                                            const int* __restrict__ staging,
                                            int* __restrict__ edge_src,
                                            int* __restrict__ row_ptr, int N,
                                            char* smem) {
    int* lhist = (int*)smem;        // [256]
    int* lscan = lhist + 256;       // [256]
    int* lcur = lscan + 256;        // [256]
    int t = threadIdx.x;            // 0..511
    int node_base = b << 8;
    int nn = N - node_base;
    if (nn > 256) nn = 256;
    int cnt = bcur[b * 16];
    int base = bbase[b];
    const int* stg = staging + (size_t)b * BCAP;

    if (t < 256) lhist[t] = 0;
    __syncthreads();
    for (int i = t; i < cnt; i += 512)
        atomicAdd(&lhist[((unsigned)stg[i]) >> 24], 1);
    __syncthreads();
    int v = (t < 256) ? lhist[t] : 0;
    if (t < 256) lscan[t] = v;
    __syncthreads();
    for (int off = 1; off < 256; off <<= 1) {
        int u = (t >= off && t < 256) ? lscan[t - off] : 0;
        __syncthreads();
        if (t < 256) lscan[t] += u;
        __syncthreads();
    }
    int excl = (t < 256) ? (lscan[t] - v) : 0;
    if (t < nn) row_ptr[node_base + t] = base + excl;
    if (t < 256) {
        lscan[t] = excl;
        lcur[t] = 0;
    }
    __syncthreads();
    for (int i = t; i < cnt; i += 512) {
        int w = stg[i];
        int ln = ((unsigned)w) >> 24;
        int src = w & 0xFFFFFF;
        int pos = base + lscan[ln] + atomicAdd(&lcur[ln], 1);
        edge_src[pos] = src;
    }
}

// GEMM: H = x @ [W_l;W_r]^T.  Hl -> fp8 e4m3 gather table, Hr + b_l -> bf16.
// 512 thr = 8 waves, each owning 64 rows x 32 cols (acc[4][2] = 32 AGPR).
// A(x) staged ONCE into 32KB LDS (reg-staged f32->bf16, blk^=(r&7) swizzle);
// two barrier-free k-loops (col halves); B = Wf (fragment-major, L2-hot):
// every load is a fully-coalesced 64-lane x 16B fetch.
__device__ __forceinline__ void gemm_body(int bid, const float* __restrict__ x,
                                          const bf16_t* __restrict__ Wf,
                                          const float* __restrict__ b_l,
                                          unsigned char* __restrict__ Hq,
                                          bf16_t* __restrict__ Hr, int M,
                                          char* smem) {
    bf16_t* A_lds = (bf16_t*)smem;  // [64][256] = 32 KB

    const int tid = threadIdx.x;
    const int lane = tid & 63;
    const int wid = tid >> 6;       // 0..7 -> 32-col strip
    const int lr = lane & 15;
    const int lh = lane >> 4;
    const int row0 = bid * BM;
    const int cb = wid * 32;        // strip base col (within pass)
    const int s4 = wid >> 1;        // 64-col super-strip for Wf layout
    const int nt0 = (wid & 1) * 2;  // first global n-tile of this strip

#pragma unroll
    for (int o = 0; o < 4; ++o) {
        int idx = o * 512 + tid;    // 2048 slots = 64 rows x 32 blocks
        int r = idx >> 5;
        int j = idx & 31;
        int gr = row0 + r;
        if (gr > M - 1) gr = M - 1;
        int lb = j ^ (r & 7);
        float4 u0 = *(const float4*)(x + (size_t)gr * D + lb * 8);
        float4 u1 = *(const float4*)(x + (size_t)gr * D + lb * 8 + 4);
        bf16x8 v = {(bf16_t)u0.x, (bf16_t)u0.y, (bf16_t)u0.z, (bf16_t)u0.w,
                    (bf16_t)u1.x, (bf16_t)u1.y, (bf16_t)u1.z, (bf16_t)u1.w};
        *(bf16x8*)&A_lds[idx * 8] = v;
    }
    __syncthreads();

    f32x4_t acc[4][2];

    // fragment-major B: chunk(p, s, kk, nt) at elems
    // p*65536 + s*16384 + kk*2048 + nt*512; lane's 16B at +lane*8
    const bf16_t* wps = Wf + (size_t)s4 * 16384 + nt0 * 512 + lane * 8;

#define KLOOP(P)                                                               \
    _Pragma("unroll") for (int k0 = 0; k0 < 256; k0 += 32) {                   \
        const int kk = k0 >> 5;                                                \
        const int kb = (k0 >> 3) + lh;                                         \
        bf16x8 a[4], b[2];                                                     \
        _Pragma("unroll") for (int mt = 0; mt < 4; mt++) {                     \
            int ra = mt * 16 + lr;                                             \
            a[mt] = *(const bf16x8*)&A_lds[ra * D + ((kb ^ (ra & 7)) << 3)];   \
        }                                                                      \
        _Pragma("unroll") for (int nt = 0; nt < 2; nt++)                       \
            b[nt] = *(const bf16x8*)(wps + ((P) * 65536 + kk * 2048 +          \
                                            nt * 512));                       \
        _Pragma("unroll") for (int mt = 0; mt < 4; mt++)                       \
            _Pragma("unroll") for (int nt = 0; nt < 2; nt++)                   \
                acc[mt][nt] = __builtin_amdgcn_mfma_f32_16x16x32_bf16(         \
                    a[mt], b[nt], acc[mt][nt], 0, 0, 0);                       \
    }

    // pass 1: Hl = x @ W_l^T -> fp8
#pragma unroll
    for (int i = 0; i < 4; i++)
#pragma unroll
        for (int j = 0; j < 2; j++) acc[i][j] = (f32x4_t){0.f, 0.f, 0.f, 0.f};
    KLOOP(0)
#pragma unroll
    for (int mt = 0; mt < 4; mt++) {
#pragma unroll
        for (int r = 0; r < 4; r++) {
            int m = row0 + mt * 16 + lh * 4 + r;
            if (m < M) {
#pragma unroll
                for (int nt = 0; nt < 2; nt++) {
                    int c = cb + nt * 16 + lr;
                    float u = acc[mt][nt][r];
                    int w = __builtin_amdgcn_cvt_pk_fp8_f32(u, u, 0, false);
                    Hq[(size_t)m * D + c] = (unsigned char)(w & 0xff);
                }
            }
        }
    }

    // pass 2: Hr = x @ W_r^T + b_l -> bf16
    float bl[2];
#pragma unroll
    for (int nt = 0; nt < 2; nt++) bl[nt] = b_l[cb + nt * 16 + lr];
#pragma unroll
    for (int i = 0; i < 4; i++)
#pragma unroll
        for (int j = 0; j < 2; j++) acc[i][j] = (f32x4_t){0.f, 0.f, 0.f, 0.f};
    KLOOP(1)
#undef KLOOP
#pragma unroll
    for (int mt = 0; mt < 4; mt++) {
#pragma unroll
        for (int r = 0; r < 4; r++) {
            int m = row0 + mt * 16 + lh * 4 + r;
            if (m < M) {
#pragma unroll
                for (int nt = 0; nt < 2; nt++) {
                    int c = cb + nt * 16 + lr;
                    Hr[(size_t)m * D + c] = (bf16_t)(acc[mt][nt][r] + bl[nt]);
                }
            }
        }
    }
}

// ---------------- super-kernels (512 threads) ----------------

// K1: scatter blocks [0, nScatter) || GEMM rows [0, nGemm1*BM)
__global__ __launch_bounds__(512) void k_sg(const int* __restrict__ eidx,
                                            int* __restrict__ bcur,
                                            int* __restrict__ staging, int E,
                                            const float* __restrict__ x,
                                            const bf16_t* __restrict__ Wf,
                                            const float* __restrict__ b_l,
                                            unsigned char* __restrict__ Hq,
                                            bf16_t* __restrict__ Hr, int M,
                                            int nScatter) {
    __shared__ __align__(16) char smem[BM * D * sizeof(bf16_t)];
    int b = blockIdx.x;
    if (b < nScatter)
        scatter_body(b, eidx, bcur, staging, E, smem);
    else
        gemm_body(b - nScatter, x, Wf, b_l, Hq, Hr, M, smem);
}

// K2: bucket blocks [0, B1) || GEMM rows [gemmOff*BM, ...)
__global__ __launch_bounds__(512) void k_bg(const int* __restrict__ bcur,
                                            const int* __restrict__ bbase,
                                            const int* __restrict__ staging,
                                            int* __restrict__ edge_src,
                                            int* __restrict__ row_ptr, int N,
                                            const float* __restrict__ x,
                                            const bf16_t* __restrict__ Wf,
                                            const float* __restrict__ b_l,
                                            unsigned char* __restrict__ Hq,
                                            bf16_t* __restrict__ Hr,
                                            int B1, int gemmOff) {
    __shared__ __align__(16) char smem[BM * D * sizeof(bf16_t)];
    int b = blockIdx.x;
    if (b < B1)
        bucket_body(b, bcur, bbase, staging, edge_src, row_ptr, N, smem);
    else
        gemm_body(b - B1 + gemmOff, x, Wf, b_l, Hq, Hr, N, smem);
}

// scan of bucket counts -> bucket base offsets (B1 <= 512)
__global__ __launch_bounds__(512) void k_bbase(const int* __restrict__ bcur,
                                               int* __restrict__ bbase,
                                               int* __restrict__ row_ptr,
                                               int B1, int N, int E) {
    __shared__ int sm[512];
    int t = threadIdx.x;
    int v = (t < B1) ? bcur[t * 16] : 0;
    sm[t] = v;
    __syncthreads();
    for (int off = 1; off < 512; off <<= 1) {
        int u = (t >= off) ? sm[t - off] : 0;
        __syncthreads();
        sm[t] += u;
        __syncthreads();
    }
    if (t < B1) bbase[t] = sm[t] - v;  // exclusive
    if (t == 0) row_ptr[N] = E;
}

// --------- weights: Wf fragment-major.  Chunk (p,s,kk,nt) = 512 bf16:
// element (lane,j) = W_p[s*64 + nt*16 + (lane&15)][kk*32 + (lane>>4)*8 + j] --

__global__ __launch_bounds__(256) void k_convw(const float* __restrict__ Wl,
                                               const float* __restrict__ Wr,
                                               bf16_t* __restrict__ Wf) {
    int i = blockIdx.x * 256 + threadIdx.x;  // one thread = 4 elems
    if (i >= KDIM * D / 4) return;
    int o = i * 4;
    int e = o & 511;          // element within chunk
    int c = o >> 9;           // chunk id
    int lane = e >> 3;
    int j0 = e & 7;           // 0 or 4
    int nt = c & 3;
    int kk = (c >> 2) & 7;
    int s = (c >> 5) & 3;
    int p = c >> 7;
    int row = s * 64 + nt * 16 + (lane & 15);
    int col = kk * 32 + (lane >> 4) * 8 + j0;
    const float* src = (p == 0) ? (Wl + (size_t)row * D + col)
                                : (Wr + (size_t)row * D + col);
    float4 v = *(const float4*)src;
    bf16x4 ov = {(bf16_t)v.x, (bf16_t)v.y, (bf16_t)v.z, (bf16_t)v.w};
    *(bf16x4*)(Wf + o) = ov;
}

// ------- FINAL: wave-per-node gather-mean of Hq + Hr + GELU + LN + residual.
// Main loop UNROLLED x2 (16 edges/iter, 4 independent 4-row gathers in
// flight) to double memory-level parallelism; x1 loop + masked tail for
// remainders. Packed f32x2 accumulation. Zero LDS. --------------------------

__global__ __launch_bounds__(256) void k_final(
        const int* __restrict__ row_ptr, const int* __restrict__ edge_src,
        const unsigned char* __restrict__ Hq, const bf16_t* __restrict__ Hr,
        const float* __restrict__ x, const float* __restrict__ gamma,
        const float* __restrict__ beta, float* __restrict__ out, int N) {
    int wv = threadIdx.x >> 6;
    int lane = threadIdx.x & 63;
    int node = blockIdx.x * 4 + wv;
    if (node >= N) return;
    int g = lane >> 4;       // row subgroup in gather / column quad in epilogue
    int c16 = lane & 15;     // 16-fp8 column chunk
    int beg = row_ptr[node];
    int end = row_ptr[node + 1];
    const uint4* hb = (const uint4*)Hq;  // 16 uint4 per row

    f32x2_t acc2[8];
#pragma unroll
    for (int k = 0; k < 8; k++) acc2[k] = (f32x2_t){0.f, 0.f};

#define ACC4(w, i)                                                \
    {                                                             \
        acc2[i] += __builtin_amdgcn_cvt_pk_f32_fp8((w), false);   \
        acc2[(i) + 1] += __builtin_amdgcn_cvt_pk_f32_fp8((w), true); \
    }

    int j = beg;
    for (; j + 16 <= end; j += 16) {  // x2-unrolled main loop: 4 gathers in flight
        int s0 = edge_src[j + g];
        int s1 = edge_src[j + 4 + g];
        int s2 = edge_src[j + 8 + g];
        int s3 = edge_src[j + 12 + g];
        uint4 v0 = hb[(s0 << 4) + c16];
        uint4 v1 = hb[(s1 << 4) + c16];
        uint4 v2 = hb[(s2 << 4) + c16];
        uint4 v3 = hb[(s3 << 4) + c16];
        ACC4(v0.x, 0) ACC4(v0.y, 2) ACC4(v0.z, 4) ACC4(v0.w, 6)
        ACC4(v1.x, 0) ACC4(v1.y, 2) ACC4(v1.z, 4) ACC4(v1.w, 6)
        ACC4(v2.x, 0) ACC4(v2.y, 2) ACC4(v2.z, 4) ACC4(v2.w, 6)
        ACC4(v3.x, 0) ACC4(v3.y, 2) ACC4(v3.z, 4) ACC4(v3.w, 6)
    }
    for (; j + 8 <= end; j += 8) {  // x1 loop
        int s0 = edge_src[j + g];
        int s1 = edge_src[j + 4 + g];
        uint4 v0 = hb[(s0 << 4) + c16];
        uint4 v1 = hb[(s1 << 4) + c16];
        ACC4(v0.x, 0) ACC4(v0.y, 2) ACC4(v0.z, 4) ACC4(v0.w, 6)
        ACC4(v1.x, 0) ACC4(v1.y, 2) ACC4(v1.z, 4) ACC4(v1.w, 6)
    }
    if (j < end) {  // masked tail (<= 7 edges)
        int j0 = j + g, j1 = j + 4 + g;
        bool ok0 = j0 < end, ok1 = j1 < end;
        int s0 = edge_src[ok0 ? j0 : beg];
        int s1 = edge_src[ok1 ? j1 : beg];
        uint4 v0 = hb[(s0 << 4) + c16];
        uint4 v1 = hb[(s1 << 4) + c16];
        if (!ok0) { v0.x = 0; v0.y = 0; v0.z = 0; v0.w = 0; }
        if (!ok1) { v1.x = 0; v1.y = 0; v1.z = 0; v1.w = 0; }
        ACC4(v0.x, 0) ACC4(v0.y, 2) ACC4(v0.z, 4) ACC4(v0.w, 6)
        ACC4(v1.x, 0) ACC4(v1.y, 2) ACC4(v1.z, 4) ACC4(v1.w, 6)
    }
#undef ACC4

    float accf[16];
#pragma unroll
    for (int k = 0; k < 16; k++) accf[k] = acc2[k >> 1][k & 1];
    // combine the 4 row-subgroups -> all lanes hold the full chunk
#pragma unroll
    for (int k = 0; k < 16; k++) {
        accf[k] += __shfl_xor(accf[k], 16, 64);
        accf[k] += __shfl_xor(accf[k], 32, 64);
    }
    int dg = end - beg;
    float inv = 1.0f / (float)(dg > 0 ? dg : 1);

    // lane takes cols [col0, col0+4): agg-mean + Hr (bias folded) -> GELU
    int col0 = c16 * 16 + g * 4;
    bf16x4 hr = *(const bf16x4*)(Hr + (size_t)node * D + col0);
    float v[4];
    float s = 0.f, ss = 0.f;
#pragma unroll
    for (int j2 = 0; j2 < 4; j2++) {
        float t = (g == 0) ? accf[j2]
                : (g == 1) ? accf[4 + j2]
                : (g == 2) ? accf[8 + j2]
                           : accf[12 + j2];
        float u = t * inv + (float)hr[j2];
        float ge = 0.5f * u * (1.0f + erff(u * 0.70710678118654752f));
        v[j2] = ge;
        s += ge;
        ss += ge * ge;
    }
    // full-wave LayerNorm reduction (all 64 lanes hold distinct columns)
#pragma unroll
    for (int off = 1; off <= 32; off <<= 1) {
        s += __shfl_xor(s, off, 64);
        ss += __shfl_xor(ss, off, 64);
    }
    float mean = s * (1.0f / 256.0f);
    float var = ss * (1.0f / 256.0f) - mean * mean;
    float rstd = rsqrtf(var + 1e-5f);

    float4 ga = *(const float4*)(gamma + col0);
    float4 be = *(const float4*)(beta + col0);
    float4 xr = *(const float4*)(x + (size_t)node * D + col0);
    float4 o;
#pragma unroll
    for (int j2 = 0; j2 < 4; j2++)
        (&o.x)[j2] = (v[j2] - mean) * rstd * (&ga.x)[j2] + (&be.x)[j2] +
                     (&xr.x)[j2];
    *(float4*)(out + (size_t)node * D + col0) = o;
}

// ---------------- launch ----------------

extern "C" void kernel_launch(void* const* d_in, const int* in_sizes, int n_in,
                              void* d_out, int out_size, void* d_ws, size_t ws_size,
                              hipStream_t stream) {
    const float* x = (const float*)d_in[0];
    const int* eidx = (const int*)d_in[1];
    const float* W_l = (const float*)d_in[2];
    const float* b_l = (const float*)d_in[3];
    const float* W_r = (const float*)d_in[4];
    const float* gamma = (const float*)d_in[5];
    const float* beta = (const float*)d_in[6];
    float* out = (float*)d_out;

    const int N = in_sizes[0] / D;
    const int E = in_sizes[1] / 2;
    const int B1 = (N + 255) >> 8;          // 256-node buckets (391)
    const int SB = (E + EPB - 1) / EPB;     // scatter blocks (391)
    const int GB = (N + BM - 1) / BM;       // gemm blocks (1563)
    const int GB1 = (GB + 1) / 2;           // gemm blocks in K1

    char* basep = (char*)d_ws;
    size_t off = 0;
    auto take = [&](size_t bytes) -> void* {
        void* r = basep + off;
        off += (bytes + 255) & ~(size_t)255;
        return r;
    };
    bf16_t* Hr = (bf16_t*)take((size_t)N * D * sizeof(bf16_t));        // 51.2 MB
    unsigned char* Hq = (unsigned char*)take((size_t)N * D);           // 25.6 MB
    int* staging = (int*)take((size_t)B1 * BCAP * sizeof(int));        // 25.6 MB
    int* edge_src = (int*)take((size_t)E * sizeof(int));               // 12.8 MB
    bf16_t* Wf = (bf16_t*)take((size_t)KDIM * D * sizeof(bf16_t));     // 256 KB
    int* row_ptr = (int*)take((size_t)(N + 1) * sizeof(int));
    int* bcur = (int*)take((size_t)B1 * 16 * sizeof(int));
    int* bbase = (int*)take((size_t)B1 * sizeof(int));

    hipMemsetAsync(bcur, 0, (size_t)B1 * 16 * sizeof(int), stream);

    k_convw<<<(KDIM * D / 4 + 255) / 256, 256, 0, stream>>>(W_l, W_r, Wf);

    // K1: scatter || gemm rows [0, GB1*BM)
    k_sg<<<SB + GB1, 512, 0, stream>>>(eidx, bcur, staging, E, x, Wf, b_l,
                                       Hq, Hr, N, SB);
    k_bbase<<<1, 512, 0, stream>>>(bcur, bbase, row_ptr, B1, N, E);
    // K2: bucket || gemm rows [GB1*BM, N)
    k_bg<<<B1 + (GB - GB1), 512, 0, stream>>>(bcur, bbase, staging, edge_src,
                                              row_ptr, N, x, Wf, b_l, Hq,
                                              Hr, B1, GB1);

    k_final<<<(N + 3) / 4, 256, 0, stream>>>(row_ptr, edge_src, Hq, Hr, x,
                                             gamma, beta, out, N);
}

// Round 16
// 279.321 us; speedup vs baseline: 1.0147x; 1.0147x over previous
//
#include <hip/hip_runtime.h>

#define D 256
#define KDIM 512
#define BCAP 16384  // per-bucket staging capacity (avg fill 8192 for E=3.2M, B1=391)
#define EPB 8192    // edges per scatter block
#define BM 32       // rows per GEMM block

typedef __bf16 bf16_t;
typedef bf16_t bf16x8 __attribute__((ext_vector_type(8)));
typedef bf16_t bf16x4 __attribute__((ext_vector_type(4)));
typedef float f32x4_t __attribute__((ext_vector_type(4)));
typedef float f32x2_t __attribute__((ext_vector_type(2)));

// ---------------- device bodies (512-thread grid-partitioned super-kernels)

// coarse scatter into 256-node buckets (block-aggregated; write-amp ~1x)
__device__ __forceinline__ void scatter_body(int bid, const int* __restrict__ eidx,
                                             int* __restrict__ bcur,
                                             int* __restrict__ staging, int E,
                                             char* smem) {
    int* lhist = (int*)smem;        // [512]
    int* lcur = lhist + 512;        // [512]
    int* gbase = lcur + 512;        // [512]
    const int t = threadIdx.x;      // 0..511
    const int e0 = bid * EPB;
    int e1 = e0 + EPB;
    if (e1 > E) e1 = E;

    lhist[t] = 0;
    lcur[t] = 0;
    __syncthreads();

    for (int e = e0 + t; e < e1; e += 512) {
        int d = eidx[E + e];
        atomicAdd(&lhist[d >> 8], 1);
    }
    __syncthreads();

    {
        int c = lhist[t];
        gbase[t] = (c > 0) ? atomicAdd(&bcur[t * 16], c) : 0;
    }
    __syncthreads();

    for (int e = e0 + t; e < e1; e += 512) {
        int s = eidx[e];
        int d = eidx[E + e];
        int b = d >> 8;
        int pos = gbase[b] + atomicAdd(&lcur[b], 1);
        staging[(size_t)b * BCAP + pos] = ((d & 255) << 24) | s;  // s < 2^24
    }
}

// per-bucket hist + scan + counting-sort; emits row_ptr AND edge_src
__device__ __forceinline__ void bucket_body(int b, const int* __restrict__ bcur,
                                            const int* __restrict__ bbase,
                                            const int* __restrict__ staging,
                                            int* __restrict__ edge_src,
                                            int* __restrict__ row_ptr, int N,
                                            char* smem) {
    int* lhist = (int*)smem;        // [256]
    int* lscan = lhist + 256;       // [256]
    int* lcur = lscan + 256;        // [256]
    int t = threadIdx.x;            // 0..511
    int node_base = b << 8;
    int nn = N - node_base;
    if (nn > 256) nn = 256;
    int cnt = bcur[b * 16];
    int base = bbase[b];
    const int* stg = staging + (size_t)b * BCAP;

    if (t < 256) lhist[t] = 0;
    __syncthreads();
    for (int i = t; i < cnt; i += 512)
        atomicAdd(&lhist[((unsigned)stg[i]) >> 24], 1);
    __syncthreads();
    int v = (t < 256) ? lhist[t] : 0;
    if (t < 256) lscan[t] = v;
    __syncthreads();
    for (int off = 1; off < 256; off <<= 1) {
        int u = (t >= off && t < 256) ? lscan[t - off] : 0;
        __syncthreads();
        if (t < 256) lscan[t] += u;
        __syncthreads();
    }
    int excl = (t < 256) ? (lscan[t] - v) : 0;
    if (t < nn) row_ptr[node_base + t] = base + excl;
    if (t < 256) {
        lscan[t] = excl;
        lcur[t] = 0;
    }
    __syncthreads();
    for (int i = t; i < cnt; i += 512) {
        int w = stg[i];
        int ln = ((unsigned)w) >> 24;
        int src = w & 0xFFFFFF;
        int pos = base + lscan[ln] + atomicAdd(&lcur[ln], 1);
        edge_src[pos] = src;
    }
}

// GEMM: H = x @ [W_l;W_r]^T.  Hl -> fp8 e4m3 gather table, Hr + b_l -> bf16.
// 512 thr = 8 waves, each owning 32 rows x 32 cols (acc[2][2] = 16 AGPR) —
// minimal register footprint; 16KB LDS A-panel -> up to 4 blocks/CU (32
// waves, full occupancy). Barrier-free k-loops; B = Wf (fragment-major,
// L2-hot): every load is a fully-coalesced 64-lane x 16B fetch.
__device__ __forceinline__ void gemm_body(int bid, const float* __restrict__ x,
                                          const bf16_t* __restrict__ Wf,
                                          const float* __restrict__ b_l,
                                          unsigned char* __restrict__ Hq,
                                          bf16_t* __restrict__ Hr, int M,
                                          char* smem) {
    bf16_t* A_lds = (bf16_t*)smem;  // [32][256] = 16 KB

    const int tid = threadIdx.x;
    const int lane = tid & 63;
    const int wid = tid >> 6;       // 0..7 -> 32-col strip
    const int lr = lane & 15;
    const int lh = lane >> 4;
    const int row0 = bid * BM;
    const int cb = wid * 32;        // strip base col (within pass)
    const int s4 = wid >> 1;        // 64-col super-strip for Wf layout
    const int nt0 = (wid & 1) * 2;  // first global n-tile of this strip

#pragma unroll
    for (int o = 0; o < 2; ++o) {
        int idx = o * 512 + tid;    // 1024 slots = 32 rows x 32 blocks
        int r = idx >> 5;
        int j = idx & 31;
        int gr = row0 + r;
        if (gr > M - 1) gr = M - 1;
        int lb = j ^ (r & 7);
        float4 u0 = *(const float4*)(x + (size_t)gr * D + lb * 8);
        float4 u1 = *(const float4*)(x + (size_t)gr * D + lb * 8 + 4);
        bf16x8 v = {(bf16_t)u0.x, (bf16_t)u0.y, (bf16_t)u0.z, (bf16_t)u0.w,
                    (bf16_t)u1.x, (bf16_t)u1.y, (bf16_t)u1.z, (bf16_t)u1.w};
        *(bf16x8*)&A_lds[idx * 8] = v;
    }
    __syncthreads();

    f32x4_t acc[2][2];

    // fragment-major B: chunk(p, s, kk, nt) at elems
    // p*65536 + s*16384 + kk*2048 + nt*512; lane's 16B at +lane*8
    const bf16_t* wps = Wf + (size_t)s4 * 16384 + nt0 * 512 + lane * 8;

#define KLOOP(P)                                                               \
    _Pragma("unroll") for (int k0 = 0; k0 < 256; k0 += 32) {                   \
        const int kk = k0 >> 5;                                                \
        const int kb = (k0 >> 3) + lh;                                         \
        bf16x8 a[2], b[2];                                                     \
        _Pragma("unroll") for (int mt = 0; mt < 2; mt++) {                     \
            int ra = mt * 16 + lr;                                             \
            a[mt] = *(const bf16x8*)&A_lds[ra * D + ((kb ^ (ra & 7)) << 3)];   \
        }                                                                      \
        _Pragma("unroll") for (int nt = 0; nt < 2; nt++)                       \
            b[nt] = *(const bf16x8*)(wps + ((P) * 65536 + kk * 2048 +          \
                                            nt * 512));                       \
        _Pragma("unroll") for (int mt = 0; mt < 2; mt++)                       \
            _Pragma("unroll") for (int nt = 0; nt < 2; nt++)                   \
                acc[mt][nt] = __builtin_amdgcn_mfma_f32_16x16x32_bf16(         \
                    a[mt], b[nt], acc[mt][nt], 0, 0, 0);                       \
    }

    // pass 1: Hl = x @ W_l^T -> fp8
#pragma unroll
    for (int i = 0; i < 2; i++)
#pragma unroll
        for (int j = 0; j < 2; j++) acc[i][j] = (f32x4_t){0.f, 0.f, 0.f, 0.f};
    KLOOP(0)
#pragma unroll
    for (int mt = 0; mt < 2; mt++) {
#pragma unroll
        for (int r = 0; r < 4; r++) {
            int m = row0 + mt * 16 + lh * 4 + r;
            if (m < M) {
#pragma unroll
                for (int nt = 0; nt < 2; nt++) {
                    int c = cb + nt * 16 + lr;
                    float u = acc[mt][nt][r];
                    int w = __builtin_amdgcn_cvt_pk_fp8_f32(u, u, 0, false);
                    Hq[(size_t)m * D + c] = (unsigned char)(w & 0xff);
                }
            }
        }
    }

    // pass 2: Hr = x @ W_r^T + b_l -> bf16
    float bl[2];
#pragma unroll
    for (int nt = 0; nt < 2; nt++) bl[nt] = b_l[cb + nt * 16 + lr];
#pragma unroll
    for (int i = 0; i < 2; i++)
#pragma unroll
        for (int j = 0; j < 2; j++) acc[i][j] = (f32x4_t){0.f, 0.f, 0.f, 0.f};
    KLOOP(1)
#undef KLOOP
#pragma unroll
    for (int mt = 0; mt < 2; mt++) {
#pragma unroll
        for (int r = 0; r < 4; r++) {
            int m = row0 + mt * 16 + lh * 4 + r;
            if (m < M) {
#pragma unroll
                for (int nt = 0; nt < 2; nt++) {
                    int c = cb + nt * 16 + lr;
                    Hr[(size_t)m * D + c] = (bf16_t)(acc[mt][nt][r] + bl[nt]);
                }
            }
        }
    }
}

// ---------------- super-kernels (512 threads) ----------------

// K1: scatter blocks [0, nScatter) || GEMM rows [0, nGemm1*BM)
__global__ __launch_bounds__(512) void k_sg(const int* __restrict__ eidx,
                                            int* __restrict__ bcur,
                                            int* __restrict__ staging, int E,
                                            const float* __restrict__ x,
                                            const bf16_t* __restrict__ Wf,
                                            const float* __restrict__ b_l,
                                            unsigned char* __restrict__ Hq,
                                            bf16_t* __restrict__ Hr, int M,
                                            int nScatter) {
    __shared__ __align__(16) char smem[BM * D * sizeof(bf16_t)];  // 16 KB
    int b = blockIdx.x;
    if (b < nScatter)
        scatter_body(b, eidx, bcur, staging, E, smem);
    else
        gemm_body(b - nScatter, x, Wf, b_l, Hq, Hr, M, smem);
}

// K2: bucket blocks [0, B1) || GEMM rows [gemmOff*BM, ...)
__global__ __launch_bounds__(512) void k_bg(const int* __restrict__ bcur,
                                            const int* __restrict__ bbase,
                                            const int* __restrict__ staging,
                                            int* __restrict__ edge_src,
                                            int* __restrict__ row_ptr, int N,
                                            const float* __restrict__ x,
                                            const bf16_t* __restrict__ Wf,
                                            const float* __restrict__ b_l,
                                            unsigned char* __restrict__ Hq,
                                            bf16_t* __restrict__ Hr,
                                            int B1, int gemmOff) {
    __shared__ __align__(16) char smem[BM * D * sizeof(bf16_t)];  // 16 KB
    int b = blockIdx.x;
    if (b < B1)
        bucket_body(b, bcur, bbase, staging, edge_src, row_ptr, N, smem);
    else
        gemm_body(b - B1 + gemmOff, x, Wf, b_l, Hq, Hr, N, smem);
}

// scan of bucket counts -> bucket base offsets (B1 <= 512)
__global__ __launch_bounds__(512) void k_bbase(const int* __restrict__ bcur,
                                               int* __restrict__ bbase,
                                               int* __restrict__ row_ptr,
                                               int B1, int N, int E) {
    __shared__ int sm[512];
    int t = threadIdx.x;
    int v = (t < B1) ? bcur[t * 16] : 0;
    sm[t] = v;
    __syncthreads();
    for (int off = 1; off < 512; off <<= 1) {
        int u = (t >= off) ? sm[t - off] : 0;
        __syncthreads();
        sm[t] += u;
        __syncthreads();
    }
    if (t < B1) bbase[t] = sm[t] - v;  // exclusive
    if (t == 0) row_ptr[N] = E;
}

// --------- weights: Wf fragment-major.  Chunk (p,s,kk,nt) = 512 bf16:
// element (lane,j) = W_p[s*64 + nt*16 + (lane&15)][kk*32 + (lane>>4)*8 + j] --

__global__ __launch_bounds__(256) void k_convw(const float* __restrict__ Wl,
                                               const float* __restrict__ Wr,
                                               bf16_t* __restrict__ Wf) {
    int i = blockIdx.x * 256 + threadIdx.x;  // one thread = 4 elems
    if (i >= KDIM * D / 4) return;
    int o = i * 4;
    int e = o & 511;          // element within chunk
    int c = o >> 9;           // chunk id
    int lane = e >> 3;
    int j0 = e & 7;           // 0 or 4
    int nt = c & 3;
    int kk = (c >> 2) & 7;
    int s = (c >> 5) & 3;
    int p = c >> 7;
    int row = s * 64 + nt * 16 + (lane & 15);
    int col = kk * 32 + (lane >> 4) * 8 + j0;
    const float* src = (p == 0) ? (Wl + (size_t)row * D + col)
                                : (Wr + (size_t)row * D + col);
    float4 v = *(const float4*)src;
    bf16x4 ov = {(bf16_t)v.x, (bf16_t)v.y, (bf16_t)v.z, (bf16_t)v.w};
    *(bf16x4*)(Wf + o) = ov;
}

// ------- FINAL: wave-per-node gather-mean of Hq + Hr + GELU + LN + residual.
// Round-14 version (28 VGPR, ~79% occupancy — empirically at the random-
// gather throughput floor; x2-unroll regressed via occupancy loss). ---------

__global__ __launch_bounds__(256) void k_final(
        const int* __restrict__ row_ptr, const int* __restrict__ edge_src,
        const unsigned char* __restrict__ Hq, const bf16_t* __restrict__ Hr,
        const float* __restrict__ x, const float* __restrict__ gamma,
        const float* __restrict__ beta, float* __restrict__ out, int N) {
    int wv = threadIdx.x >> 6;
    int lane = threadIdx.x & 63;
    int node = blockIdx.x * 4 + wv;
    if (node >= N) return;
    int g = lane >> 4;       // row subgroup in gather / column quad in epilogue
    int c16 = lane & 15;     // 16-fp8 column chunk
    int beg = row_ptr[node];
    int end = row_ptr[node + 1];
    const uint4* hb = (const uint4*)Hq;  // 16 uint4 per row

    f32x2_t acc2[8];
#pragma unroll
    for (int k = 0; k < 8; k++) acc2[k] = (f32x2_t){0.f, 0.f};

#define ACC4(w, i)                                                \
    {                                                             \
        acc2[i] += __builtin_amdgcn_cvt_pk_f32_fp8((w), false);   \
        acc2[(i) + 1] += __builtin_amdgcn_cvt_pk_f32_fp8((w), true); \
    }

    int j = beg;
    for (; j + 8 <= end; j += 8) {  // unmasked main loop
        int s0 = edge_src[j + g];
        int s1 = edge_src[j + 4 + g];
        uint4 v0 = hb[(s0 << 4) + c16];
        uint4 v1 = hb[(s1 << 4) + c16];
        ACC4(v0.x, 0) ACC4(v0.y, 2) ACC4(v0.z, 4) ACC4(v0.w, 6)
        ACC4(v1.x, 0) ACC4(v1.y, 2) ACC4(v1.z, 4) ACC4(v1.w, 6)
    }
    if (j < end) {  // masked tail (<= 7 edges)
        int j0 = j + g, j1 = j + 4 + g;
        bool ok0 = j0 < end, ok1 = j1 < end;
        int s0 = edge_src[ok0 ? j0 : beg];
        int s1 = edge_src[ok1 ? j1 : beg];
        uint4 v0 = hb[(s0 << 4) + c16];
        uint4 v1 = hb[(s1 << 4) + c16];
        if (!ok0) { v0.x = 0; v0.y = 0; v0.z = 0; v0.w = 0; }
        if (!ok1) { v1.x = 0; v1.y = 0; v1.z = 0; v1.w = 0; }
        ACC4(v0.x, 0) ACC4(v0.y, 2) ACC4(v0.z, 4) ACC4(v0.w, 6)
        ACC4(v1.x, 0) ACC4(v1.y, 2) ACC4(v1.z, 4) ACC4(v1.w, 6)
    }
#undef ACC4

    float accf[16];
#pragma unroll
    for (int k = 0; k < 16; k++) accf[k] = acc2[k >> 1][k & 1];
    // combine the 4 row-subgroups -> all lanes hold the full chunk
#pragma unroll
    for (int k = 0; k < 16; k++) {
        accf[k] += __shfl_xor(accf[k], 16, 64);
        accf[k] += __shfl_xor(accf[k], 32, 64);
    }
    int dg = end - beg;
    float inv = 1.0f / (float)(dg > 0 ? dg : 1);

    // lane takes cols [col0, col0+4): agg-mean + Hr (bias folded) -> GELU
    int col0 = c16 * 16 + g * 4;
    bf16x4 hr = *(const bf16x4*)(Hr + (size_t)node * D + col0);
    float v[4];
    float s = 0.f, ss = 0.f;
#pragma unroll
    for (int j2 = 0; j2 < 4; j2++) {
        float t = (g == 0) ? accf[j2]
                : (g == 1) ? accf[4 + j2]
                : (g == 2) ? accf[8 + j2]
                           : accf[12 + j2];
        float u = t * inv + (float)hr[j2];
        float ge = 0.5f * u * (1.0f + erff(u * 0.70710678118654752f));
        v[j2] = ge;
        s += ge;
        ss += ge * ge;
    }
    // full-wave LayerNorm reduction (all 64 lanes hold distinct columns)
#pragma unroll
    for (int off = 1; off <= 32; off <<= 1) {
        s += __shfl_xor(s, off, 64);
        ss += __shfl_xor(ss, off, 64);
    }
    float mean = s * (1.0f / 256.0f);
    float var = ss * (1.0f / 256.0f) - mean * mean;
    float rstd = rsqrtf(var + 1e-5f);

    float4 ga = *(const float4*)(gamma + col0);
    float4 be = *(const float4*)(beta + col0);
    float4 xr = *(const float4*)(x + (size_t)node * D + col0);
    float4 o;
#pragma unroll
    for (int j2 = 0; j2 < 4; j2++)
        (&o.x)[j2] = (v[j2] - mean) * rstd * (&ga.x)[j2] + (&be.x)[j2] +
                     (&xr.x)[j2];
    *(float4*)(out + (size_t)node * D + col0) = o;
}

// ---------------- launch ----------------

extern "C" void kernel_launch(void* const* d_in, const int* in_sizes, int n_in,
                              void* d_out, int out_size, void* d_ws, size_t ws_size,
                              hipStream_t stream) {
    const float* x = (const float*)d_in[0];
    const int* eidx = (const int*)d_in[1];
    const float* W_l = (const float*)d_in[2];
    const float* b_l = (const float*)d_in[3];
    const float* W_r = (const float*)d_in[4];
    const float* gamma = (const float*)d_in[5];
    const float* beta = (const float*)d_in[6];
    float* out = (float*)d_out;

    const int N = in_sizes[0] / D;
    const int E = in_sizes[1] / 2;
    const int B1 = (N + 255) >> 8;          // 256-node buckets (391)
    const int SB = (E + EPB - 1) / EPB;     // scatter blocks (391)
    const int GB = (N + BM - 1) / BM;       // gemm blocks (3125)
    const int GB1 = (GB + 1) / 2;           // gemm blocks in K1

    char* basep = (char*)d_ws;
    size_t off = 0;
    auto take = [&](size_t bytes) -> void* {
        void* r = basep + off;
        off += (bytes + 255) & ~(size_t)255;
        return r;
    };
    bf16_t* Hr = (bf16_t*)take((size_t)N * D * sizeof(bf16_t));        // 51.2 MB
    unsigned char* Hq = (unsigned char*)take((size_t)N * D);           // 25.6 MB
    int* staging = (int*)take((size_t)B1 * BCAP * sizeof(int));        // 25.6 MB
    int* edge_src = (int*)take((size_t)E * sizeof(int));               // 12.8 MB
    bf16_t* Wf = (bf16_t*)take((size_t)KDIM * D * sizeof(bf16_t));     // 256 KB
    int* row_ptr = (int*)take((size_t)(N + 1) * sizeof(int));
    int* bcur = (int*)take((size_t)B1 * 16 * sizeof(int));
    int* bbase = (int*)take((size_t)B1 * sizeof(int));

    hipMemsetAsync(bcur, 0, (size_t)B1 * 16 * sizeof(int), stream);

    k_convw<<<(KDIM * D / 4 + 255) / 256, 256, 0, stream>>>(W_l, W_r, Wf);

    // K1: scatter || gemm rows [0, GB1*BM)
    k_sg<<<SB + GB1, 512, 0, stream>>>(eidx, bcur, staging, E, x, Wf, b_l,
                                       Hq, Hr, N, SB);
    k_bbase<<<1, 512, 0, stream>>>(bcur, bbase, row_ptr, B1, N, E);
    // K2: bucket || gemm rows [GB1*BM, N)
    k_bg<<<B1 + (GB - GB1), 512, 0, stream>>>(bcur, bbase, staging, edge_src,
                                              row_ptr, N, x, Wf, b_l, Hq,
                                              Hr, B1, GB1);

    k_final<<<(N + 3) / 4, 256, 0, stream>>>(row_ptr, edge_src, Hq, Hr, x,
                                             gamma, beta, out, N);
}

// Round 17
// 277.941 us; speedup vs baseline: 1.0197x; 1.0050x over previous
//
#include <hip/hip_runtime.h>

#define D 256
#define KDIM 512
#define BCAP 16384  // per-bucket staging capacity (avg fill 8192 for E=3.2M, B1=391)
#define EPB 8192    // edges per scatter block
#define BM 32       // rows per GEMM block

typedef __bf16 bf16_t;
typedef bf16_t bf16x8 __attribute__((ext_vector_type(8)));
typedef bf16_t bf16x4 __attribute__((ext_vector_type(4)));
typedef float f32x4_t __attribute__((ext_vector_type(4)));
typedef float f32x2_t __attribute__((ext_vector_type(2)));

// ---------------- device bodies (512-thread grid-partitioned super-kernels)

// coarse scatter into 256-node buckets (block-aggregated; write-amp ~1x)
__device__ __forceinline__ void scatter_body(int bid, const int* __restrict__ eidx,
                                             int* __restrict__ bcur,
                                             int* __restrict__ staging, int E,
                                             char* smem) {
    int* lhist = (int*)smem;        // [512]
    int* lcur = lhist + 512;        // [512]
    int* gbase = lcur + 512;        // [512]
    const int t = threadIdx.x;      // 0..511
    const int e0 = bid * EPB;
    int e1 = e0 + EPB;
    if (e1 > E) e1 = E;

    lhist[t] = 0;
    lcur[t] = 0;
    __syncthreads();

    for (int e = e0 + t; e < e1; e += 512) {
        int d = eidx[E + e];
        atomicAdd(&lhist[d >> 8], 1);
    }
    __syncthreads();

    {
        int c = lhist[t];
        gbase[t] = (c > 0) ? atomicAdd(&bcur[t * 16], c) : 0;
    }
    __syncthreads();

    for (int e = e0 + t; e < e1; e += 512) {
        int s = eidx[e];
        int d = eidx[E + e];
        int b = d >> 8;
        int pos = gbase[b] + atomicAdd(&lcur[b], 1);
        staging[(size_t)b * BCAP + pos] = ((d & 255) << 24) | s;  // s < 2^24
    }
}

// per-bucket hist + scan + counting-sort; emits row_ptr AND edge_src
__device__ __forceinline__ void bucket_body(int b, const int* __restrict__ bcur,
                                            const int* __restrict__ bbase,
                                            const int* __restrict__ staging,
                                            int* __restrict__ edge_src,
                                            int* __restrict__ row_ptr, int N,
                                            char* smem) {
    int* lhist = (int*)smem;        // [256]
    int* lscan = lhist + 256;       // [256]
    int* lcur = lscan + 256;        // [256]
    int t = threadIdx.x;            // 0..511
    int node_base = b << 8;
    int nn = N - node_base;
    if (nn > 256) nn = 256;
    int cnt = bcur[b * 16];
    int base = bbase[b];
    const int* stg = staging + (size_t)b * BCAP;

    if (t < 256) lhist[t] = 0;
    __syncthreads();
    for (int i = t; i < cnt; i += 512)
        atomicAdd(&lhist[((unsigned)stg[i]) >> 24], 1);
    __syncthreads();
    int v = (t < 256) ? lhist[t] : 0;
    if (t < 256) lscan[t] = v;
    __syncthreads();
    for (int off = 1; off < 256; off <<= 1) {
        int u = (t >= off && t < 256) ? lscan[t - off] : 0;
        __syncthreads();
        if (t < 256) lscan[t] += u;
        __syncthreads();
    }
    int excl = (t < 256) ? (lscan[t] - v) : 0;
    if (t < nn) row_ptr[node_base + t] = base + excl;
    if (t < 256) {
        lscan[t] = excl;
        lcur[t] = 0;
    }
    __syncthreads();
    for (int i = t; i < cnt; i += 512) {
        int w = stg[i];
        int ln = ((unsigned)w) >> 24;
        int src = w & 0xFFFFFF;
        int pos = base + lscan[ln] + atomicAdd(&lcur[ln], 1);
        edge_src[pos] = src;
    }
}

// GEMM: H = x @ [W_l;W_r]^T.  Hl -> fp8 e4m3 gather table, Hr + b_l -> bf16.
// 512 thr = 8 waves, each owning 32 rows x 32 cols. MERGED single k-loop
// computes both passes at once: acc[2][2][2] (32 regs), each of 8 iterations
// does {2 LDS a-loads + 4 b-loads + 8 MFMA} — a-fragments amortized across
// both weight halves, half the loop latency exposure of two passes.
// B = Wf (fragment-major, L2-hot): fully-coalesced 64-lane x 16B fetches.
__device__ __forceinline__ void gemm_body(int bid, const float* __restrict__ x,
                                          const bf16_t* __restrict__ Wf,
                                          const float* __restrict__ b_l,
                                          unsigned char* __restrict__ Hq,
                                          bf16_t* __restrict__ Hr, int M,
                                          char* smem) {
    bf16_t* A_lds = (bf16_t*)smem;  // [32][256] = 16 KB

    const int tid = threadIdx.x;
    const int lane = tid & 63;
    const int wid = tid >> 6;       // 0..7 -> 32-col strip
    const int lr = lane & 15;
    const int lh = lane >> 4;
    const int row0 = bid * BM;
    const int cb = wid * 32;        // strip base col (within pass)
    const int s4 = wid >> 1;        // 64-col super-strip for Wf layout
    const int nt0 = (wid & 1) * 2;  // first global n-tile of this strip

#pragma unroll
    for (int o = 0; o < 2; ++o) {
        int idx = o * 512 + tid;    // 1024 slots = 32 rows x 32 blocks
        int r = idx >> 5;
        int j = idx & 31;
        int gr = row0 + r;
        if (gr > M - 1) gr = M - 1;
        int lb = j ^ (r & 7);
        float4 u0 = *(const float4*)(x + (size_t)gr * D + lb * 8);
        float4 u1 = *(const float4*)(x + (size_t)gr * D + lb * 8 + 4);
        bf16x8 v = {(bf16_t)u0.x, (bf16_t)u0.y, (bf16_t)u0.z, (bf16_t)u0.w,
                    (bf16_t)u1.x, (bf16_t)u1.y, (bf16_t)u1.z, (bf16_t)u1.w};
        *(bf16x8*)&A_lds[idx * 8] = v;
    }
    __syncthreads();

    f32x4_t acc[2][2][2];  // [pass][mt][nt]
#pragma unroll
    for (int p = 0; p < 2; p++)
#pragma unroll
        for (int i = 0; i < 2; i++)
#pragma unroll
            for (int j = 0; j < 2; j++)
                acc[p][i][j] = (f32x4_t){0.f, 0.f, 0.f, 0.f};

    // fragment-major B: chunk(p, s, kk, nt) at elems
    // p*65536 + s*16384 + kk*2048 + nt*512; lane's 16B at +lane*8
    const bf16_t* wps = Wf + (size_t)s4 * 16384 + nt0 * 512 + lane * 8;

#pragma unroll
    for (int k0 = 0; k0 < 256; k0 += 32) {
        const int kk = k0 >> 5;
        const int kb = (k0 >> 3) + lh;
        bf16x8 a[2], b0[2], b1[2];
#pragma unroll
        for (int mt = 0; mt < 2; mt++) {
            int ra = mt * 16 + lr;
            a[mt] = *(const bf16x8*)&A_lds[ra * D + ((kb ^ (ra & 7)) << 3)];
        }
#pragma unroll
        for (int nt = 0; nt < 2; nt++) {
            b0[nt] = *(const bf16x8*)(wps + (kk * 2048 + nt * 512));
            b1[nt] = *(const bf16x8*)(wps + (65536 + kk * 2048 + nt * 512));
        }
#pragma unroll
        for (int mt = 0; mt < 2; mt++)
#pragma unroll
            for (int nt = 0; nt < 2; nt++) {
                acc[0][mt][nt] = __builtin_amdgcn_mfma_f32_16x16x32_bf16(
                    a[mt], b0[nt], acc[0][mt][nt], 0, 0, 0);
                acc[1][mt][nt] = __builtin_amdgcn_mfma_f32_16x16x32_bf16(
                    a[mt], b1[nt], acc[1][mt][nt], 0, 0, 0);
            }
    }

    // epilogue pass 1: Hl -> fp8
#pragma unroll
    for (int mt = 0; mt < 2; mt++) {
#pragma unroll
        for (int r = 0; r < 4; r++) {
            int m = row0 + mt * 16 + lh * 4 + r;
            if (m < M) {
#pragma unroll
                for (int nt = 0; nt < 2; nt++) {
                    int c = cb + nt * 16 + lr;
                    float u = acc[0][mt][nt][r];
                    int w = __builtin_amdgcn_cvt_pk_fp8_f32(u, u, 0, false);
                    Hq[(size_t)m * D + c] = (unsigned char)(w & 0xff);
                }
            }
        }
    }

    // epilogue pass 2: Hr = x @ W_r^T + b_l -> bf16
    float bl[2];
#pragma unroll
    for (int nt = 0; nt < 2; nt++) bl[nt] = b_l[cb + nt * 16 + lr];
#pragma unroll
    for (int mt = 0; mt < 2; mt++) {
#pragma unroll
        for (int r = 0; r < 4; r++) {
            int m = row0 + mt * 16 + lh * 4 + r;
            if (m < M) {
#pragma unroll
                for (int nt = 0; nt < 2; nt++) {
                    int c = cb + nt * 16 + lr;
                    Hr[(size_t)m * D + c] = (bf16_t)(acc[1][mt][nt][r] + bl[nt]);
                }
            }
        }
    }
}

// ---------------- super-kernels (512 threads) ----------------

// K1: scatter blocks [0, nScatter) || GEMM rows [0, nGemm1*BM)
__global__ __launch_bounds__(512) void k_sg(const int* __restrict__ eidx,
                                            int* __restrict__ bcur,
                                            int* __restrict__ staging, int E,
                                            const float* __restrict__ x,
                                            const bf16_t* __restrict__ Wf,
                                            const float* __restrict__ b_l,
                                            unsigned char* __restrict__ Hq,
                                            bf16_t* __restrict__ Hr, int M,
                                            int nScatter) {
    __shared__ __align__(16) char smem[BM * D * sizeof(bf16_t)];  // 16 KB
    int b = blockIdx.x;
    if (b < nScatter)
        scatter_body(b, eidx, bcur, staging, E, smem);
    else
        gemm_body(b - nScatter, x, Wf, b_l, Hq, Hr, M, smem);
}

// K2: bucket blocks [0, B1) || GEMM rows [gemmOff*BM, ...)
__global__ __launch_bounds__(512) void k_bg(const int* __restrict__ bcur,
                                            const int* __restrict__ bbase,
                                            const int* __restrict__ staging,
                                            int* __restrict__ edge_src,
                                            int* __restrict__ row_ptr, int N,
                                            const float* __restrict__ x,
                                            const bf16_t* __restrict__ Wf,
                                            const float* __restrict__ b_l,
                                            unsigned char* __restrict__ Hq,
                                            bf16_t* __restrict__ Hr,
                                            int B1, int gemmOff) {
    __shared__ __align__(16) char smem[BM * D * sizeof(bf16_t)];  // 16 KB
    int b = blockIdx.x;
    if (b < B1)
        bucket_body(b, bcur, bbase, staging, edge_src, row_ptr, N, smem);
    else
        gemm_body(b - B1 + gemmOff, x, Wf, b_l, Hq, Hr, N, smem);
}

// scan of bucket counts -> bucket base offsets (B1 <= 512)
__global__ __launch_bounds__(512) void k_bbase(const int* __restrict__ bcur,
                                               int* __restrict__ bbase,
                                               int* __restrict__ row_ptr,
                                               int B1, int N, int E) {
    __shared__ int sm[512];
    int t = threadIdx.x;
    int v = (t < B1) ? bcur[t * 16] : 0;
    sm[t] = v;
    __syncthreads();
    for (int off = 1; off < 512; off <<= 1) {
        int u = (t >= off) ? sm[t - off] : 0;
        __syncthreads();
        sm[t] += u;
        __syncthreads();
    }
    if (t < B1) bbase[t] = sm[t] - v;  // exclusive
    if (t == 0) row_ptr[N] = E;
}

// --------- weights: Wf fragment-major.  Chunk (p,s,kk,nt) = 512 bf16:
// element (lane,j) = W_p[s*64 + nt*16 + (lane&15)][kk*32 + (lane>>4)*8 + j] --

__global__ __launch_bounds__(256) void k_convw(const float* __restrict__ Wl,
                                               const float* __restrict__ Wr,
                                               bf16_t* __restrict__ Wf) {
    int i = blockIdx.x * 256 + threadIdx.x;  // one thread = 4 elems
    if (i >= KDIM * D / 4) return;
    int o = i * 4;
    int e = o & 511;          // element within chunk
    int c = o >> 9;           // chunk id
    int lane = e >> 3;
    int j0 = e & 7;           // 0 or 4
    int nt = c & 3;
    int kk = (c >> 2) & 7;
    int s = (c >> 5) & 3;
    int p = c >> 7;
    int row = s * 64 + nt * 16 + (lane & 15);
    int col = kk * 32 + (lane >> 4) * 8 + j0;
    const float* src = (p == 0) ? (Wl + (size_t)row * D + col)
                                : (Wr + (size_t)row * D + col);
    float4 v = *(const float4*)src;
    bf16x4 ov = {(bf16_t)v.x, (bf16_t)v.y, (bf16_t)v.z, (bf16_t)v.w};
    *(bf16x4*)(Wf + o) = ov;
}

// ------- FINAL: wave-per-node gather-mean of Hq + Hr + GELU + LN + residual.
// Round-14 version (28 VGPR, ~79% occupancy — empirically at the random-
// gather throughput floor; x2-unroll regressed via occupancy loss). ---------

__global__ __launch_bounds__(256) void k_final(
        const int* __restrict__ row_ptr, const int* __restrict__ edge_src,
        const unsigned char* __restrict__ Hq, const bf16_t* __restrict__ Hr,
        const float* __restrict__ x, const float* __restrict__ gamma,
        const float* __restrict__ beta, float* __restrict__ out, int N) {
    int wv = threadIdx.x >> 6;
    int lane = threadIdx.x & 63;
    int node = blockIdx.x * 4 + wv;
    if (node >= N) return;
    int g = lane >> 4;       // row subgroup in gather / column quad in epilogue
    int c16 = lane & 15;     // 16-fp8 column chunk
    int beg = row_ptr[node];
    int end = row_ptr[node + 1];
    const uint4* hb = (const uint4*)Hq;  // 16 uint4 per row

    f32x2_t acc2[8];
#pragma unroll
    for (int k = 0; k < 8; k++) acc2[k] = (f32x2_t){0.f, 0.f};

#define ACC4(w, i)                                                \
    {                                                             \
        acc2[i] += __builtin_amdgcn_cvt_pk_f32_fp8((w), false);   \
        acc2[(i) + 1] += __builtin_amdgcn_cvt_pk_f32_fp8((w), true); \
    }

    int j = beg;
    for (; j + 8 <= end; j += 8) {  // unmasked main loop
        int s0 = edge_src[j + g];
        int s1 = edge_src[j + 4 + g];
        uint4 v0 = hb[(s0 << 4) + c16];
        uint4 v1 = hb[(s1 << 4) + c16];
        ACC4(v0.x, 0) ACC4(v0.y, 2) ACC4(v0.z, 4) ACC4(v0.w, 6)
        ACC4(v1.x, 0) ACC4(v1.y, 2) ACC4(v1.z, 4) ACC4(v1.w, 6)
    }
    if (j < end) {  // masked tail (<= 7 edges)
        int j0 = j + g, j1 = j + 4 + g;
        bool ok0 = j0 < end, ok1 = j1 < end;
        int s0 = edge_src[ok0 ? j0 : beg];
        int s1 = edge_src[ok1 ? j1 : beg];
        uint4 v0 = hb[(s0 << 4) + c16];
        uint4 v1 = hb[(s1 << 4) + c16];
        if (!ok0) { v0.x = 0; v0.y = 0; v0.z = 0; v0.w = 0; }
        if (!ok1) { v1.x = 0; v1.y = 0; v1.z = 0; v1.w = 0; }
        ACC4(v0.x, 0) ACC4(v0.y, 2) ACC4(v0.z, 4) ACC4(v0.w, 6)
        ACC4(v1.x, 0) ACC4(v1.y, 2) ACC4(v1.z, 4) ACC4(v1.w, 6)
    }
#undef ACC4

    float accf[16];
#pragma unroll
    for (int k = 0; k < 16; k++) accf[k] = acc2[k >> 1][k & 1];
    // combine the 4 row-subgroups -> all lanes hold the full chunk
#pragma unroll
    for (int k = 0; k < 16; k++) {
        accf[k] += __shfl_xor(accf[k], 16, 64);
        accf[k] += __shfl_xor(accf[k], 32, 64);
    }
    int dg = end - beg;
    float inv = 1.0f / (float)(dg > 0 ? dg : 1);

    // lane takes cols [col0, col0+4): agg-mean + Hr (bias folded) -> GELU
    int col0 = c16 * 16 + g * 4;
    bf16x4 hr = *(const bf16x4*)(Hr + (size_t)node * D + col0);
    float v[4];
    float s = 0.f, ss = 0.f;
#pragma unroll
    for (int j2 = 0; j2 < 4; j2++) {
        float t = (g == 0) ? accf[j2]
                : (g == 1) ? accf[4 + j2]
                : (g == 2) ? accf[8 + j2]
                           : accf[12 + j2];
        float u = t * inv + (float)hr[j2];
        float ge = 0.5f * u * (1.0f + erff(u * 0.70710678118654752f));
        v[j2] = ge;
        s += ge;
        ss += ge * ge;
    }
    // full-wave LayerNorm reduction (all 64 lanes hold distinct columns)
#pragma unroll
    for (int off = 1; off <= 32; off <<= 1) {
        s += __shfl_xor(s, off, 64);
        ss += __shfl_xor(ss, off, 64);
    }
    float mean = s * (1.0f / 256.0f);
    float var = ss * (1.0f / 256.0f) - mean * mean;
    float rstd = rsqrtf(var + 1e-5f);

    float4 ga = *(const float4*)(gamma + col0);
    float4 be = *(const float4*)(beta + col0);
    float4 xr = *(const float4*)(x + (size_t)node * D + col0);
    float4 o;
#pragma unroll
    for (int j2 = 0; j2 < 4; j2++)
        (&o.x)[j2] = (v[j2] - mean) * rstd * (&ga.x)[j2] + (&be.x)[j2] +
                     (&xr.x)[j2];
    *(float4*)(out + (size_t)node * D + col0) = o;
}

// ---------------- launch ----------------

extern "C" void kernel_launch(void* const* d_in, const int* in_sizes, int n_in,
                              void* d_out, int out_size, void* d_ws, size_t ws_size,
                              hipStream_t stream) {
    const float* x = (const float*)d_in[0];
    const int* eidx = (const int*)d_in[1];
    const float* W_l = (const float*)d_in[2];
    const float* b_l = (const float*)d_in[3];
    const float* W_r = (const float*)d_in[4];
    const float* gamma = (const float*)d_in[5];
    const float* beta = (const float*)d_in[6];
    float* out = (float*)d_out;

    const int N = in_sizes[0] / D;
    const int E = in_sizes[1] / 2;
    const int B1 = (N + 255) >> 8;          // 256-node buckets (391)
    const int SB = (E + EPB - 1) / EPB;     // scatter blocks (391)
    const int GB = (N + BM - 1) / BM;       // gemm blocks (3125)
    const int GB1 = (GB + 1) / 2;           // gemm blocks in K1

    char* basep = (char*)d_ws;
    size_t off = 0;
    auto take = [&](size_t bytes) -> void* {
        void* r = basep + off;
        off += (bytes + 255) & ~(size_t)255;
        return r;
    };
    bf16_t* Hr = (bf16_t*)take((size_t)N * D * sizeof(bf16_t));        // 51.2 MB
    unsigned char* Hq = (unsigned char*)take((size_t)N * D);           // 25.6 MB
    int* staging = (int*)take((size_t)B1 * BCAP * sizeof(int));        // 25.6 MB
    int* edge_src = (int*)take((size_t)E * sizeof(int));               // 12.8 MB
    bf16_t* Wf = (bf16_t*)take((size_t)KDIM * D * sizeof(bf16_t));     // 256 KB
    int* row_ptr = (int*)take((size_t)(N + 1) * sizeof(int));
    int* bcur = (int*)take((size_t)B1 * 16 * sizeof(int));
    int* bbase = (int*)take((size_t)B1 * sizeof(int));

    hipMemsetAsync(bcur, 0, (size_t)B1 * 16 * sizeof(int), stream);

    k_convw<<<(KDIM * D / 4 + 255) / 256, 256, 0, stream>>>(W_l, W_r, Wf);

    // K1: scatter || gemm rows [0, GB1*BM)
    k_sg<<<SB + GB1, 512, 0, stream>>>(eidx, bcur, staging, E, x, Wf, b_l,
                                       Hq, Hr, N, SB);
    k_bbase<<<1, 512, 0, stream>>>(bcur, bbase, row_ptr, B1, N, E);
    // K2: bucket || gemm rows [GB1*BM, N)
    k_bg<<<B1 + (GB - GB1), 512, 0, stream>>>(bcur, bbase, staging, edge_src,
                                              row_ptr, N, x, Wf, b_l, Hq,
                                              Hr, B1, GB1);

    k_final<<<(N + 3) / 4, 256, 0, stream>>>(row_ptr, edge_src, Hq, Hr, x,
                                             gamma, beta, out, N);
}